// Round 1
// baseline (292.680 us; speedup 1.0000x reference)
//
#include <hip/hip_runtime.h>
#include <hip/hip_bf16.h>

// Problem constants
constexpr int N   = 32;
constexpr int C   = 16;    // in channels
constexpr int H   = 256;
constexpr int W   = 256;
constexpr int CO  = 16;    // out channels
constexpr int OH  = 254;
constexpr int OW  = 254;
constexpr float SUBV = 0.7f;   // SUB1 + SUB2

// GEMM-view: k = (ky*3+kx)*16 + ci, K=144 padded to 160 (5 chunks of 32)
constexpr int KPAD = 160;

// Tiling
constexpr int TY    = 10;          // output rows per block (was 14; smaller -> 6 blocks/CU)
constexpr int TIN_Y = TY + 2;      // 12 staged input rows
constexpr int TX    = 64;          // output px per block (4 waves x 16)
constexpr int TIN_X = TX + 2;      // 66
// Plane-separated LDS layout: plane h holds ci[8h..8h+7] of every site, 16 B/site,
// no padding. Per-wave ds_read_b128 is bank-phase-uniform (8 lanes per 128B slot).
constexpr int SITE_US = 8;                  // ushorts per site per plane (16 B)
constexpr int ROW_US  = TIN_X * SITE_US;    // 528 ushorts per row per plane
constexpr int PS      = TIN_Y * ROW_US;     // 6336 ushorts plane stride
// total LDS: 2*PS ushorts = 25344 B -> 6 blocks/CU (152 KiB), 24 waves/CU

using short8  = __attribute__((ext_vector_type(8))) short;
using floatx4 = __attribute__((ext_vector_type(4))) float;

__device__ inline uint bf16u(float f) {           // RNE float->bf16 bits (inputs are finite)
    uint u = __builtin_bit_cast(uint, f);
    u += 0x7fffu + ((u >> 16) & 1u);
    return u >> 16;
}

// ---------------------------------------------------------------------------
// Kernel 1: weights -> bf16, k-reordered A-matrix [co][KPAD]; k<144 real, rest 0.
// Bias (fp32, -0.7 folded) appended at ushort offset 2560 (byte 5120).
// ---------------------------------------------------------------------------
__global__ void reorder_weights(const float* __restrict__ w,
                                const float* __restrict__ b,
                                ushort* __restrict__ wr) {
    const int t = threadIdx.x;
    for (int i = t; i < CO * KPAD; i += 256) {
        const int co = i / KPAD;
        const int k  = i - co * KPAD;
        ushort v = 0;
        if (k < 144) {
            const int pair = k >> 4;          // ky*3+kx, 0..8
            const int ci   = k & 15;
            const int ky   = pair / 3;
            const int kx   = pair - 3 * ky;
            v = (ushort)bf16u(w[((co * C + ci) * 3 + ky) * 3 + kx]);
        }
        wr[i] = v;
    }
    if (t < CO) ((float*)(wr + CO * KPAD))[t] = b[t] - SUBV;
}

// ---------------------------------------------------------------------------
// Kernel 2: implicit-GEMM conv3x3 via bf16 MFMA 16x16x32, fused bias+mish.
// Block 256 thr = 4 waves. Wave w owns the 16-px column [x0+16w, +16).
// LDS: two ci-half planes, [h][y in 12][x in 66] x 16B, no pad (conflict-free
// read pattern by construction). 25344 B -> 6 blocks/CU for latency hiding.
// ---------------------------------------------------------------------------
__launch_bounds__(256, 6)
__global__ void conv_mfma(const float* __restrict__ x,
                          const ushort* __restrict__ wr,
                          float* __restrict__ out) {
    __shared__ ushort lds[2 * PS];           // 25344 B

    const int tid  = threadIdx.x;
    const int lane = tid & 63;
    const int wave = tid >> 6;
    const int quad = lane >> 4;
    const int n    = lane & 15;              // pixel within 16-px tile / co for A load

    const int x0 = blockIdx.x * TX;
    const int y0 = blockIdx.y * TY;
    const int ni = blockIdx.z;

    // ---- per-lane A fragments (weights), loaded from global (L2-hot) ----
    short8 afrag[5];
    {
        const ushort* wbase = wr + n * KPAD + quad * 8;   // A[m=co=n][k=32c+8*quad+j]
        #pragma unroll
        for (int c = 0; c < 5; ++c)
            afrag[c] = *(const short8*)(wbase + c * 32);
    }
    // bias for this lane's 4 co values (co = quad*4 + j)
    float bias_j[4];
    {
        const float* bp = (const float*)(wr + CO * KPAD);
        const float4 bv = *(const float4*)(bp + quad * 4);
        bias_j[0] = bv.x; bias_j[1] = bv.y; bias_j[2] = bv.z; bias_j[3] = bv.w;
    }
    // B-fragment LDS offsets (ushorts) per k-chunk; quad&1 selects ci-half plane
    int boff[5];
    #pragma unroll
    for (int c = 0; c < 5; ++c) {
        int pair = 2 * c + (quad >> 1);
        if (pair > 8) pair = 8;              // pad chunk reads real data x zero weights
        const int ky = pair / 3;
        const int kx = pair - 3 * ky;
        boff[c] = (quad & 1) * PS + ky * ROW_US + (n + kx) * SITE_US;
    }
    // output store bases (co = quad*4 + j)
    size_t obase[4];
    const int oxv = x0 + wave * 16 + n;
    const bool oxok = oxv < OW;
    #pragma unroll
    for (int j = 0; j < 4; ++j)
        obase[j] = ((size_t)(ni * CO + quad * 4 + j)) * OH * OW + oxv;

    // ---- stage input tile: global fp32 [ci][y][x] -> LDS bf16 planes ----
    {
        const float* xs = x + (size_t)ni * C * H * W;
        for (int sp = tid; sp < (TIN_Y * TIN_X) / 2; sp += 256) {   // 396 site-pairs
            const int s  = sp * 2;
            const int yy = s / TIN_X;
            const int xx = s - yy * TIN_X;                           // even; pair stays in row (66 even)
            const int iy  = (y0 + yy < H - 1) ? (y0 + yy) : (H - 1); // clamped cells feed only masked outputs
            const int ixp = (x0 + xx < W - 2) ? (x0 + xx) : (W - 2);
            const float* src = xs + (size_t)iy * W + ixp;
            uint a[8], b[8];
            #pragma unroll
            for (int ci = 0; ci < C; ci += 2) {
                const float2 p0 = *(const float2*)(src + (size_t)ci * H * W);
                const float2 p1 = *(const float2*)(src + (size_t)(ci + 1) * H * W);
                a[ci >> 1] = bf16u(p0.x) | (bf16u(p1.x) << 16);
                b[ci >> 1] = bf16u(p0.y) | (bf16u(p1.y) << 16);
            }
            ushort* d0 = &lds[(yy * TIN_X + xx) * SITE_US];          // site s, plane0
            ((uint4*)d0)[0]        = make_uint4(a[0], a[1], a[2], a[3]);
            ((uint4*)(d0 + PS))[0] = make_uint4(a[4], a[5], a[6], a[7]);  // site s, plane1
            ushort* d1 = d0 + SITE_US;                               // site s+1
            ((uint4*)d1)[0]        = make_uint4(b[0], b[1], b[2], b[3]);
            ((uint4*)(d1 + PS))[0] = make_uint4(b[4], b[5], b[6], b[7]);
        }
    }
    __syncthreads();

    // ---- K-loop per output-row pair: 10 ds_read_b128 + 10 MFMA ----
    const ushort* wcol = lds + wave * 16 * SITE_US;
    #pragma unroll 1
    for (int r = 0; r < TY; r += 2) {
        floatx4 acc0 = {0.f, 0.f, 0.f, 0.f};
        floatx4 acc1 = {0.f, 0.f, 0.f, 0.f};
        const ushort* b0 = wcol + r * ROW_US;
        const ushort* b1 = b0 + ROW_US;
        #pragma unroll
        for (int c = 0; c < 5; ++c) {
            const short8 f0 = *(const short8*)(b0 + boff[c]);
            const short8 f1 = *(const short8*)(b1 + boff[c]);
            acc0 = __builtin_amdgcn_mfma_f32_16x16x32_bf16(afrag[c], f0, acc0, 0, 0, 0);
            acc1 = __builtin_amdgcn_mfma_f32_16x16x32_bf16(afrag[c], f1, acc1, 0, 0, 0);
        }
        // epilogue: D col = lane&15 = pix, row = quad*4+reg = co
        #pragma unroll
        for (int rr = 0; rr < 2; ++rr) {
            const int oy = y0 + r + rr;
            if (oy < OH && oxok) {
                const floatx4 av = rr ? acc1 : acc0;
                #pragma unroll
                for (int j = 0; j < 4; ++j) {
                    const float v  = av[j] + bias_j[j];
                    const float vc = fminf(v, 15.0f);        // tanh saturated beyond
                    const float e  = __expf(vc);
                    const float z  = 1.0f + e;
                    const float z2 = z * z;
                    const float t  = __fdividef(z2 - 1.0f, z2 + 1.0f);
                    out[obase[j] + (size_t)oy * OW] = v * t; // mish
                }
            }
        }
    }
}

extern "C" void kernel_launch(void* const* d_in, const int* in_sizes, int n_in,
                              void* d_out, int out_size, void* d_ws, size_t ws_size,
                              hipStream_t stream) {
    const float* x = (const float*)d_in[0];
    const float* w = (const float*)d_in[1];
    const float* b = (const float*)d_in[2];
    float* out = (float*)d_out;
    ushort* wr = (ushort*)d_ws;   // 2560*2 + 16*4 = 5184 bytes

    hipLaunchKernelGGL(reorder_weights, dim3(1), dim3(256), 0, stream, w, b, wr);

    dim3 grid(OW / TX + 1, (OH + TY - 1) / TY, N);   // 4 x 26 x 32
    hipLaunchKernelGGL(conv_mfma, grid, dim3(256), 0, stream, x, wr, out);
}

// Round 3
// 288.273 us; speedup vs baseline: 1.0153x; 1.0153x over previous
//
#include <hip/hip_runtime.h>
#include <hip/hip_bf16.h>

// Problem constants
constexpr int N   = 32;
constexpr int C   = 16;    // in channels
constexpr int H   = 256;
constexpr int W   = 256;
constexpr int CO  = 16;    // out channels
constexpr int OH  = 254;
constexpr int OW  = 254;
constexpr float SUBV = 0.7f;   // SUB1 + SUB2

// GEMM-view: k = (ky*3+kx)*16 + ci, K=144 padded to 160 (5 chunks of 32)
constexpr int KPAD = 160;

// Tiling
constexpr int TY     = 10;          // output rows per block
constexpr int TIN_Y  = TY + 2;      // 12 staged input rows
constexpr int TX     = 64;          // output px per block (4 waves x 16)
constexpr int TIN_XS = 68;          // staged sites per row (66 needed, 4-aligned)
// Plane-separated LDS: plane h holds ci[8h..8h+7], 16 B/site, no padding.
constexpr int SITE_US = 8;                   // ushorts per site per plane (16 B)
constexpr int ROW_US  = TIN_XS * SITE_US;    // 544 ushorts per row per plane
constexpr int PS      = TIN_Y * ROW_US;      // 6528 ushorts plane stride
// total LDS: 2*PS ushorts = 26112 B

using short8  = __attribute__((ext_vector_type(8))) short;
using floatx4 = __attribute__((ext_vector_type(4))) float;

__device__ inline uint bf16u(float f) {           // RNE float->bf16 bits (inputs are finite)
    uint u = __builtin_bit_cast(uint, f);
    u += 0x7fffu + ((u >> 16) & 1u);
    return u >> 16;
}
__device__ inline uint pkbf(float lo, float hi) { // v_cvt_pk_bf16_f32 (RNE), lo in low 16
    __hip_bfloat162 h = __float22bfloat162_rn(make_float2(lo, hi));
    uint r;
    __builtin_memcpy(&r, &h, sizeof(r));
    return r;
}

// ---------------------------------------------------------------------------
// Kernel 1: weights -> bf16, k-reordered A-matrix [co][KPAD]; k<144 real, rest 0.
// Bias (fp32, -0.7 folded) appended at ushort offset 2560 (byte 5120).
// ---------------------------------------------------------------------------
__global__ void reorder_weights(const float* __restrict__ w,
                                const float* __restrict__ b,
                                ushort* __restrict__ wr) {
    const int t = threadIdx.x;
    for (int i = t; i < CO * KPAD; i += 256) {
        const int co = i / KPAD;
        const int k  = i - co * KPAD;
        ushort v = 0;
        if (k < 144) {
            const int pair = k >> 4;          // ky*3+kx, 0..8
            const int ci   = k & 15;
            const int ky   = pair / 3;
            const int kx   = pair - 3 * ky;
            v = (ushort)bf16u(w[((co * C + ci) * 3 + ky) * 3 + kx]);
        }
        wr[i] = v;
    }
    if (t < CO) ((float*)(wr + CO * KPAD))[t] = b[t] - SUBV;
}

// ---------------------------------------------------------------------------
// Kernel 2: implicit-GEMM conv3x3 via bf16 MFMA 16x16x32, fused bias+mish.
// Block 256 thr = 4 waves. Wave w owns the 16-px column [x0+16w, +16).
// Staging: one 4-site quad per thread (204 active), 16x dwordx4 issued as one
// batch (max memory-level parallelism), packed bf16 convert, 8x ds_write_b128.
// ---------------------------------------------------------------------------
__launch_bounds__(256, 4)
__global__ void conv_mfma(const float* __restrict__ x,
                          const ushort* __restrict__ wr,
                          float* __restrict__ out) {
    __shared__ ushort lds[2 * PS];           // 26112 B

    const int tid  = threadIdx.x;
    const int lane = tid & 63;
    const int wave = tid >> 6;
    const int quad = lane >> 4;
    const int n    = lane & 15;              // pixel within 16-px tile / co for A load

    const int x0 = blockIdx.x * TX;
    const int y0 = blockIdx.y * TY;
    const int ni = blockIdx.z;

    // ---- stage, phase 1: issue all 16 plane loads (1 KB/lane in flight) ----
    const bool active = tid < TIN_Y * (TIN_XS / 4);   // 204 threads
    int yy = 0, qx = 0;
    float4 v[16];
    if (active) {
        yy = tid / 17;
        qx = tid - yy * 17;
        const int iy = (y0 + yy < H - 1) ? (y0 + yy) : (H - 1);   // clamped rows feed only masked oy
        int bx = x0 + qx * 4;
        if (bx > W - 4) bx = W - 4;                               // clamped quads feed only masked ox
        const float* src = x + (size_t)ni * C * H * W + (size_t)iy * W + bx;
        #pragma unroll
        for (int ci = 0; ci < C; ++ci)
            v[ci] = *(const float4*)(src + (size_t)ci * H * W);
    }

    // ---- per-lane A fragments / bias / offsets (overlaps load latency) ----
    short8 afrag[5];
    {
        const ushort* wbase = wr + n * KPAD + quad * 8;   // A[m=co=n][k=32c+8*quad+j]
        #pragma unroll
        for (int c = 0; c < 5; ++c)
            afrag[c] = *(const short8*)(wbase + c * 32);
    }
    float bias_j[4];
    {
        const float* bp = (const float*)(wr + CO * KPAD);
        const float4 bv = *(const float4*)(bp + quad * 4);
        bias_j[0] = bv.x; bias_j[1] = bv.y; bias_j[2] = bv.z; bias_j[3] = bv.w;
    }
    int boff[5];
    #pragma unroll
    for (int c = 0; c < 5; ++c) {
        int pair = 2 * c + (quad >> 1);
        if (pair > 8) pair = 8;              // pad chunk reads real data x zero weights
        const int ky = pair / 3;
        const int kx = pair - 3 * ky;
        boff[c] = (quad & 1) * PS + ky * ROW_US + (n + kx) * SITE_US;
    }
    size_t obase[4];
    const int oxv = x0 + wave * 16 + n;
    const bool oxok = oxv < OW;
    #pragma unroll
    for (int j = 0; j < 4; ++j)
        obase[j] = ((size_t)(ni * CO + quad * 4 + j)) * OH * OW + oxv;

    // ---- stage, phase 2: pack to bf16 planes and write LDS ----
    if (active) {
        ushort* d = &lds[(yy * TIN_XS + qx * 4) * SITE_US];
        #pragma unroll
        for (int j = 0; j < 4; ++j) {
            ushort* d0 = d + j * SITE_US;
            *(uint4*)d0 = make_uint4(pkbf(v[0][j],  v[1][j]),  pkbf(v[2][j],  v[3][j]),
                                     pkbf(v[4][j],  v[5][j]),  pkbf(v[6][j],  v[7][j]));
            *(uint4*)(d0 + PS) = make_uint4(pkbf(v[8][j],  v[9][j]),  pkbf(v[10][j], v[11][j]),
                                            pkbf(v[12][j], v[13][j]), pkbf(v[14][j], v[15][j]));
        }
    }
    __syncthreads();

    // ---- K-loop per output-row pair: 10 ds_read_b128 + 10 MFMA ----
    const ushort* wcol = lds + wave * 16 * SITE_US;
    #pragma unroll 1
    for (int r = 0; r < TY; r += 2) {
        floatx4 acc0 = {0.f, 0.f, 0.f, 0.f};
        floatx4 acc1 = {0.f, 0.f, 0.f, 0.f};
        const ushort* b0 = wcol + r * ROW_US;
        const ushort* b1 = b0 + ROW_US;
        #pragma unroll
        for (int c = 0; c < 5; ++c) {
            const short8 f0 = *(const short8*)(b0 + boff[c]);
            const short8 f1 = *(const short8*)(b1 + boff[c]);
            acc0 = __builtin_amdgcn_mfma_f32_16x16x32_bf16(afrag[c], f0, acc0, 0, 0, 0);
            acc1 = __builtin_amdgcn_mfma_f32_16x16x32_bf16(afrag[c], f1, acc1, 0, 0, 0);
        }
        // epilogue: D col = lane&15 = pix, row = quad*4+reg = co
        #pragma unroll
        for (int rr = 0; rr < 2; ++rr) {
            const int oy = y0 + r + rr;
            if (oy < OH && oxok) {
                const floatx4 av = rr ? acc1 : acc0;
                #pragma unroll
                for (int j = 0; j < 4; ++j) {
                    const float v2 = av[j] + bias_j[j];
                    const float vc = fminf(v2, 15.0f);       // tanh saturated beyond
                    const float e  = __expf(vc);
                    const float z  = 1.0f + e;
                    const float z2 = z * z;
                    const float t  = __fdividef(z2 - 1.0f, z2 + 1.0f);
                    out[obase[j] + (size_t)oy * OW] = v2 * t; // mish
                }
            }
        }
    }
}

extern "C" void kernel_launch(void* const* d_in, const int* in_sizes, int n_in,
                              void* d_out, int out_size, void* d_ws, size_t ws_size,
                              hipStream_t stream) {
    const float* x = (const float*)d_in[0];
    const float* w = (const float*)d_in[1];
    const float* b = (const float*)d_in[2];
    float* out = (float*)d_out;
    ushort* wr = (ushort*)d_ws;   // 2560*2 + 16*4 = 5184 bytes

    hipLaunchKernelGGL(reorder_weights, dim3(1), dim3(256), 0, stream, w, b, wr);

    dim3 grid(OW / TX + 1, (OH + TY - 1) / TY, N);   // 4 x 26 x 32
    hipLaunchKernelGGL(conv_mfma, grid, dim3(256), 0, stream, x, wr, out);
}